// Round 1
// 178.594 us; speedup vs baseline: 1.0068x; 1.0068x over previous
//
#include <hip/hip_runtime.h>

// Embedding gather: out[t, :] = weight[ids[t], :]
// B*S = 8192 tokens, D = 1024 fp32 per row (4 KiB).
//
// Restructure vs previous version: one WAVE per token row (not one block),
// each lane moves 4 x float4 = 16 floats (64 lanes * 16 = 1024).
// Each wave handles 2 tokens with both ids preloaded, so each lane has
// 8 independent 16B loads in flight (128 B/lane MLP) instead of 1.
// Blocks: 8192 -> 1024 (8 tokens/block), cutting block/wave churn 8x/4x.

#define D_DIM 1024

__global__ __launch_bounds__(256) void embed_gather_kernel(
    const int* __restrict__ ids,
    const float* __restrict__ weight,
    float* __restrict__ out,
    int n_tokens)
{
    const int lane = (int)(threadIdx.x & 63u);   // lane within wave
    const int wave = (int)(threadIdx.x >> 6);    // 0..3
    const int nwaves = (int)gridDim.x * 4;       // total waves in grid
    const int t0 = (int)blockIdx.x * 4 + wave;   // first token for this wave
    const int t1 = t0 + nwaves;                  // second token (second half)

    if (t0 >= n_tokens) return;
    const bool has1 = (t1 < n_tokens);

    // Wave-uniform id loads (issued together, up front).
    const int row0 = ids[t0];
    const int row1 = has1 ? ids[t1] : row0;  // alias row0 so loads stay unconditional

    const float4* __restrict__ s0 =
        reinterpret_cast<const float4*>(weight + (size_t)row0 * D_DIM) + lane;
    const float4* __restrict__ s1 =
        reinterpret_cast<const float4*>(weight + (size_t)row1 * D_DIM) + lane;
    float4* __restrict__ d0 =
        reinterpret_cast<float4*>(out + (size_t)t0 * D_DIM) + lane;
    float4* __restrict__ d1 =
        reinterpret_cast<float4*>(out + (size_t)t1 * D_DIM) + lane;

    // 8 independent 16B loads in flight before any store needs a waitcnt.
    float4 a0 = s0[0], a1 = s0[64], a2 = s0[128], a3 = s0[192];
    float4 b0 = s1[0], b1 = s1[64], b2 = s1[128], b3 = s1[192];

    d0[0]   = a0; d0[64]  = a1; d0[128] = a2; d0[192] = a3;
    if (has1) {
        d1[0]   = b0; d1[64]  = b1; d1[128] = b2; d1[192] = b3;
    }
}

extern "C" void kernel_launch(void* const* d_in, const int* in_sizes, int n_in,
                              void* d_out, int out_size, void* d_ws, size_t ws_size,
                              hipStream_t stream) {
    const int*   ids    = (const int*)d_in[0];     // token_ids [B,S] int32
    const float* weight = (const float*)d_in[1];   // [VOCAB, D] fp32
    float*       out    = (float*)d_out;           // [B,S,D] fp32

    const int n_tokens = in_sizes[0];              // B*S = 8192

    // 4 waves/block * 2 tokens/wave = 8 tokens per block.
    const int blocks = (n_tokens + 7) / 8;         // 1024 for 8192 tokens
    embed_gather_kernel<<<blocks, 256, 0, stream>>>(ids, weight, out, n_tokens);
}